// Round 2
// baseline (524.905 us; speedup 1.0000x reference)
//
#include <hip/hip_runtime.h>
#include <hip/hip_bf16.h>

#define NTOK 16384
#define SQRT_C 11.313708498984761f
#define QSCALE 0.17677669529663687f
#define ROWP 152   // padded LDS row (shorts): 304 B = 76 dw == 12 banks, 16B-aligned

typedef __attribute__((ext_vector_type(8))) short v8s;   // 8 bf16 (4 VGPRs)
typedef __attribute__((ext_vector_type(4))) short v4s;   // 4 bf16 (8B)
typedef __attribute__((ext_vector_type(4))) float v4f;   // 4 fp32

__device__ inline short f2bf(float f) {
    __hip_bfloat16 h = __float2bfloat16(f);
    return __builtin_bit_cast(short, h);
}
__device__ inline float bf2f(short s) {
    unsigned u = ((unsigned)(unsigned short)s) << 16;
    return __builtin_bit_cast(float, u);
}
// LDS-only barrier: orders ds ops across waves WITHOUT draining vmcnt,
// so register prefetch of x stays in flight across tile boundaries.
__device__ inline void lds_barrier() {
    __builtin_amdgcn_sched_barrier(0);
    asm volatile("s_waitcnt lgkmcnt(0)" ::: "memory");
    __builtin_amdgcn_s_barrier();
    __builtin_amdgcn_sched_barrier(0);
}

// ---------------- K0: wbf[o][c] = bf16(w_qkv[o][c] * g1[c])  (g1 folded) -------
__global__ void k0_cvt(const float* __restrict__ wq, const float* __restrict__ g1,
                       short* __restrict__ wbf) {
    int i = blockIdx.x * 256 + threadIdx.x;   // 49152
    wbf[i] = f2bf(wq[i] * g1[i & 127]);
}

// ---------------- K1: qkv MFMA on raw bf16(x); rms-scale folded into logits ----
// grid 1024 = 16 b x 64 chunks of 256 tokens; 256 thr (4 waves); 8 tiles of 32 t.
// 4 blocks/CU (LDS 40448 B, VGPR capped 128). Wave w owns qkv rows 96w..96w+95
// and ctx head w.
__global__ __launch_bounds__(256, 4) void k1_qkv(
    const float* __restrict__ x, const short* __restrict__ wbf,
    short* __restrict__ qfrag, float* __restrict__ pS, float* __restrict__ pC)
{
    __shared__ __align__(16) short xn[32][ROWP];    // bf16(x) [t][c]
    __shared__ __align__(16) short kvbuf[256][40];  // exp(k) rows 0..127, v rows 128..255
    __shared__ __align__(16) short qbufT[32][ROWP]; // q_soft bf16 [t][c]  (transposed)
    __shared__ __align__(16) float nrm[4][32];      // per-wave sumsq partials

    const int tid = threadIdx.x;
    const int lane = tid & 63;
    const int w = tid >> 6;
    const int qd = lane >> 4;          // quad 0..3
    const int lm = lane & 15;
    const int b = blockIdx.x >> 6;
    const int chunk = blockIdx.x & 63;
    const size_t xbase = (size_t)b * 128 * NTOK;
    const int crow = tid >> 3;         // channel sub-row 0..31
    const int tq4 = (tid & 7) * 4;     // token offset within tile

    // preload W A-fragments (g1 pre-folded): rows 96w..96w+95, K=128
    v8s wA[6][4];
    #pragma unroll
    for (int rg = 0; rg < 6; ++rg)
        #pragma unroll
        for (int kk = 0; kk < 4; ++kk)
            wA[rg][kk] = *(const v8s*)(wbf + (96 * w + rg * 16 + lm) * 128 + kk * 32 + qd * 8);

    v4f cacc[2][2];
    #pragma unroll
    for (int i = 0; i < 2; ++i)
        #pragma unroll
        for (int j = 0; j < 2; ++j)
            cacc[i][j] = (v4f){0.f, 0.f, 0.f, 0.f};
    float accSr[6][4] = {};            // in-reg exp(k) row sums (k-rgs only)

    // x register buffer: thread holds channels {32p+crow}, tokens tq4..tq4+3
    v4f xv[4];
    auto loadx = [&](int tt) {
        #pragma unroll
        for (int p = 0; p < 4; ++p)
            xv[p] = *(const v4f*)(x + xbase + (size_t)(p * 32 + crow) * NTOK + tt + tq4);
    };
    loadx(chunk * 256);                // prologue prefetch (tile 0)

    for (int st = 0; st < 8; ++st) {
        const int t0 = chunk * 256 + st * 32;

        // ---- (a) sumsq reduce + bf16 convert + next-tile prefetch ----
        float s[4];
        #pragma unroll
        for (int j = 0; j < 4; ++j) {
            float acc = 0.f;
            #pragma unroll
            for (int p = 0; p < 4; ++p) { float v = xv[p][j]; acc += v * v; }
            s[j] = acc;
        }
        #pragma unroll
        for (int j = 0; j < 4; ++j) {
            s[j] += __shfl_xor(s[j], 8, 64);
            s[j] += __shfl_xor(s[j], 16, 64);
            s[j] += __shfl_xor(s[j], 32, 64);
        }
        if (lane < 8) *(v4f*)&nrm[w][lane * 4] = (v4f){s[0], s[1], s[2], s[3]};
        #pragma unroll
        for (int p = 0; p < 4; ++p)
            #pragma unroll
            for (int j = 0; j < 4; ++j)
                xn[tq4 + j][p * 32 + crow] = f2bf(xv[p][j]);
        if (st < 7) loadx(t0 + 32);    // prefetch next tile
        lds_barrier();

        // ---- (b) qkv MFMA + scl + softmax/exp distribute ----
        v4f C[6][2];
        #pragma unroll
        for (int rg = 0; rg < 6; ++rg) {
            C[rg][0] = (v4f){0.f, 0.f, 0.f, 0.f};
            C[rg][1] = (v4f){0.f, 0.f, 0.f, 0.f};
        }
        #pragma unroll
        for (int kk = 0; kk < 4; ++kk) {
            v8s B0 = *(const v8s*)&xn[lm][kk * 32 + qd * 8];
            v8s B1 = *(const v8s*)&xn[16 + lm][kk * 32 + qd * 8];
            #pragma unroll
            for (int rg = 0; rg < 6; ++rg) {
                C[rg][0] = __builtin_amdgcn_mfma_f32_16x16x32_bf16(wA[rg][kk], B0, C[rg][0], 0, 0, 0);
                C[rg][1] = __builtin_amdgcn_mfma_f32_16x16x32_bf16(wA[rg][kk], B1, C[rg][1], 0, 0, 0);
            }
        }
        // per-token rms scale for this lane's two columns (t = lm, 16+lm)
        float sA = nrm[0][lm] + nrm[1][lm] + nrm[2][lm] + nrm[3][lm];
        float sB = nrm[0][16 + lm] + nrm[1][16 + lm] + nrm[2][16 + lm] + nrm[3][16 + lm];
        float scl0 = SQRT_C / fmaxf(sqrtf(sA), 1e-12f);
        float scl1 = SQRT_C / fmaxf(sqrtf(sB), 1e-12f);

        #pragma unroll
        for (int pr = 0; pr < 3; ++pr) {
            const int R = 96 * w + 32 * pr;
            if (R < 128) {                      // q head (rows R..R+31), softmax over d
                #pragma unroll
                for (int tg = 0; tg < 2; ++tg) {
                    const float sclt = tg ? scl1 : scl0;
                    float e0[4], e1[4];
                    float m = -1e30f;
                    #pragma unroll
                    for (int r = 0; r < 4; ++r) {
                        e0[r] = C[2 * pr][tg][r] * sclt;
                        e1[r] = C[2 * pr + 1][tg][r] * sclt;
                        m = fmaxf(m, fmaxf(e0[r], e1[r]));
                    }
                    m = fmaxf(m, __shfl_xor(m, 16, 64));
                    m = fmaxf(m, __shfl_xor(m, 32, 64));
                    float ssum = 0.f;
                    #pragma unroll
                    for (int r = 0; r < 4; ++r) {
                        e0[r] = __expf(e0[r] - m);
                        e1[r] = __expf(e1[r] - m);
                        ssum += e0[r] + e1[r];
                    }
                    ssum += __shfl_xor(ssum, 16, 64);
                    ssum += __shfl_xor(ssum, 32, 64);
                    const float inv = QSCALE / ssum;
                    const int t = tg * 16 + lm;
                    v4s p0, p1;
                    #pragma unroll
                    for (int r = 0; r < 4; ++r) {
                        p0[r] = f2bf(e0[r] * inv);
                        p1[r] = f2bf(e1[r] * inv);
                    }
                    *(v4s*)&qbufT[t][R + qd * 4] = p0;          // vectorized b64 writes
                    *(v4s*)&qbufT[t][R + 16 + qd * 4] = p1;
                }
            } else {                            // k or v rows
                #pragma unroll
                for (int f = 0; f < 2; ++f) {
                    const int rg = 2 * pr + f;
                    const int R2 = R + 16 * f;
                    const bool isk = (R2 < 256);
                    float part[4] = {0.f, 0.f, 0.f, 0.f};
                    #pragma unroll
                    for (int tg = 0; tg < 2; ++tg) {
                        const float sclt = tg ? scl1 : scl0;
                        const int col = tg * 16 + lm;
                        #pragma unroll
                        for (int r = 0; r < 4; ++r) {
                            float val = C[rg][tg][r] * sclt;
                            if (isk) val = __expf(val);
                            short vb = f2bf(val);
                            kvbuf[R2 - 128 + qd * 4 + r][col] = vb;
                            if (isk) part[r] += bf2f(vb);
                        }
                    }
                    if (isk) {                  // in-reg row-sum of exp(k)
                        #pragma unroll
                        for (int r = 0; r < 4; ++r) {
                            float p = part[r];
                            p += __shfl_xor(p, 1, 64);
                            p += __shfl_xor(p, 2, 64);
                            p += __shfl_xor(p, 4, 64);
                            p += __shfl_xor(p, 8, 64);
                            accSr[rg][r] += p;
                        }
                    }
                }
            }
        }
        lds_barrier();

        // ---- (c) q gather -> global qfrag (vectorized) + context MFMA ----
        {
            const int tb0 = chunk * 16 + st * 2;
            #pragma unroll
            for (int tbl = 0; tbl < 2; ++tbl) {
                v8s pk = *(const v8s*)&qbufT[tbl * 16 + lm][w * 32 + qd * 8];
                *(v8s*)(qfrag + ((((size_t)b * 1024 + tb0 + tbl) * 4 + w) << 9) + lane * 8) = pk;
            }
            v8s A0 = *(const v8s*)&kvbuf[w * 32 + lm][qd * 8];
            v8s A1 = *(const v8s*)&kvbuf[w * 32 + 16 + lm][qd * 8];
            v8s B0 = *(const v8s*)&kvbuf[128 + w * 32 + lm][qd * 8];
            v8s B1 = *(const v8s*)&kvbuf[128 + w * 32 + 16 + lm][qd * 8];
            cacc[0][0] = __builtin_amdgcn_mfma_f32_16x16x32_bf16(A0, B0, cacc[0][0], 0, 0, 0);
            cacc[0][1] = __builtin_amdgcn_mfma_f32_16x16x32_bf16(A0, B1, cacc[0][1], 0, 0, 0);
            cacc[1][0] = __builtin_amdgcn_mfma_f32_16x16x32_bf16(A1, B0, cacc[1][0], 0, 0, 0);
            cacc[1][1] = __builtin_amdgcn_mfma_f32_16x16x32_bf16(A1, B1, cacc[1][1], 0, 0, 0);
        }
    }

    // epilogue: exp(k) row sums (waves 1,2 hold them)
    if ((w == 1 || w == 2) && lm == 0) {
        #pragma unroll
        for (int rg = 0; rg < 6; ++rg) {
            const int R = 96 * w + 16 * rg;
            if (R >= 128 && R < 256) {
                #pragma unroll
                for (int r = 0; r < 4; ++r)
                    pS[(size_t)(b * 64 + chunk) * 128 + (R - 128) + qd * 4 + r] = accSr[rg][r];
            }
        }
    }
    #pragma unroll
    for (int dg = 0; dg < 2; ++dg)
        #pragma unroll
        for (int eg = 0; eg < 2; ++eg)
            #pragma unroll
            for (int r = 0; r < 4; ++r) {
                int d = dg * 16 + qd * 4 + r;
                int e = eg * 16 + lm;
                pC[(size_t)(b * 64 + chunk) * 4096 + w * 1024 + d * 32 + e] = cacc[dg][eg][r];
            }
}

// ---------------- K2: reduce partials -> ctx -> MgT bf16 [b][o][c'] -------------
__global__ void k2_ctx(const float* __restrict__ pS, const float* __restrict__ pC,
                       const float* __restrict__ wout, short* __restrict__ MgT) {
    __shared__ float ctx[32][33];
    __shared__ float Sv[32];
    const int tid = threadIdx.x;
    const int b = blockIdx.x >> 2, h = blockIdx.x & 3;
    if (tid < 32) {
        float s = 0.f;
        for (int ch = 0; ch < 64; ++ch) s += pS[(size_t)(b * 64 + ch) * 128 + h * 32 + tid];
        Sv[tid] = s;
    }
    __syncthreads();
    #pragma unroll
    for (int k = 0; k < 4; ++k) {
        int de = tid + k * 256;
        float s = 0.f;
        for (int ch = 0; ch < 64; ++ch) s += pC[(size_t)(b * 64 + ch) * 4096 + h * 1024 + de];
        ctx[de >> 5][de & 31] = s / Sv[de >> 5];
    }
    __syncthreads();
    // M[h*32+d][o] = sum_e wout[o][h*32+e] * ctx[d][e]; store transposed bf16 at [o][h*32+d]
    #pragma unroll
    for (int k = 0; k < 16; ++k) {
        int idx = tid + k * 256;
        int d = idx & 31, o = idx >> 5;
        float m = 0.f;
        #pragma unroll
        for (int e = 0; e < 32; ++e) m += wout[o * 128 + h * 32 + e] * ctx[d][e];
        MgT[((size_t)b * 128 + o) * 128 + h * 32 + d] = f2bf(m);
    }
}

// ---------------- K3: y = M_b @ q_soft + b_out -> rmsnorm(g2) (MFMA) ------------
// grid 2048 = 16 b x 128 chunks of 128 tokens; wave w owns rows 32w..32w+31
__global__ __launch_bounds__(256) void k3_out(
    const short* __restrict__ qfrag, const short* __restrict__ MgT,
    const float* __restrict__ bo, const float* __restrict__ g2,
    float* __restrict__ out)
{
    __shared__ float part[4][128];
    __shared__ float scl[128];
    const int tid = threadIdx.x;
    const int lane = tid & 63, w = tid >> 6;
    const int qd = lane >> 4, lm = lane & 15;
    const int b = blockIdx.x >> 7;
    const int t0 = (blockIdx.x & 127) << 7;
    const int tb0 = t0 >> 4;

    v8s A[2][4];
    #pragma unroll
    for (int rg = 0; rg < 2; ++rg)
        #pragma unroll
        for (int kk = 0; kk < 4; ++kk)
            A[rg][kk] = *(const v8s*)(MgT + ((size_t)b * 128 + 32 * w + rg * 16 + lm) * 128 + kk * 32 + qd * 8);

    v4f C[2][8];
    #pragma unroll
    for (int rg = 0; rg < 2; ++rg)
        #pragma unroll
        for (int tb = 0; tb < 8; ++tb)
            C[rg][tb] = (v4f){0.f, 0.f, 0.f, 0.f};

    #pragma unroll
    for (int tb = 0; tb < 8; ++tb)
        #pragma unroll
        for (int kk = 0; kk < 4; ++kk) {
            v8s B = *(const v8s*)(qfrag + ((((size_t)b * 1024 + tb0 + tb) * 4 + kk) << 9) + lane * 8);
            C[0][tb] = __builtin_amdgcn_mfma_f32_16x16x32_bf16(A[0][kk], B, C[0][tb], 0, 0, 0);
            C[1][tb] = __builtin_amdgcn_mfma_f32_16x16x32_bf16(A[1][kk], B, C[1][tb], 0, 0, 0);
        }

    float bov[2][4], g2v[2][4];
    #pragma unroll
    for (int rg = 0; rg < 2; ++rg)
        #pragma unroll
        for (int r = 0; r < 4; ++r) {
            int o = 32 * w + rg * 16 + qd * 4 + r;
            bov[rg][r] = bo[o];
            g2v[rg][r] = g2[o];
        }
    // bias + per-token sumsq (reduce 32 rows via xor shuffles, cross-wave via LDS)
    #pragma unroll
    for (int tb = 0; tb < 8; ++tb) {
        float ss = 0.f;
        #pragma unroll
        for (int rg = 0; rg < 2; ++rg)
            #pragma unroll
            for (int r = 0; r < 4; ++r) {
                C[rg][tb][r] += bov[rg][r];
                ss += C[rg][tb][r] * C[rg][tb][r];
            }
        ss += __shfl_xor(ss, 16, 64);
        ss += __shfl_xor(ss, 32, 64);
        if (lane < 16) part[w][tb * 16 + lane] = ss;
    }
    __syncthreads();
    if (tid < 128) {
        float s = part[0][tid] + part[1][tid] + part[2][tid] + part[3][tid];
        scl[tid] = SQRT_C / fmaxf(sqrtf(s), 1e-12f);
    }
    __syncthreads();
    #pragma unroll
    for (int tb = 0; tb < 8; ++tb) {
        float sc = scl[tb * 16 + lm];
        #pragma unroll
        for (int rg = 0; rg < 2; ++rg)
            #pragma unroll
            for (int r = 0; r < 4; ++r) {
                int o = 32 * w + rg * 16 + qd * 4 + r;
                out[((size_t)b * 128 + o) * NTOK + t0 + tb * 16 + lm] = C[rg][tb][r] * sc * g2v[rg][r];
            }
    }
}

extern "C" void kernel_launch(void* const* d_in, const int* in_sizes, int n_in,
                              void* d_out, int out_size, void* d_ws, size_t ws_size,
                              hipStream_t stream) {
    const float* x    = (const float*)d_in[0];
    const float* g1   = (const float*)d_in[1];
    const float* wqkv = (const float*)d_in[2];
    const float* wout = (const float*)d_in[3];
    const float* bo   = (const float*)d_in[4];
    const float* g2   = (const float*)d_in[5];
    float* out = (float*)d_out;
    char* ws = (char*)d_ws;
    // ws: qfrag bf16 [16][1024][4][512] @0 (67,108,864 B)
    //     pS fp32 [16][64][128]  @67,108,864 (524,288)
    //     pC fp32 [16][64][4096] @67,633,152 (16,777,216)
    //     MgT bf16 [16][128][128] @84,410,368 (524,288)
    //     wbf bf16 [384][128]     @84,934,656 (98,304)   total 85,032,960 B
    short* qfrag = (short*)ws;
    float* pS = (float*)(ws + 67108864);
    float* pC = (float*)(ws + 67633152);
    short* MgT = (short*)(ws + 84410368);
    short* wbf = (short*)(ws + 84934656);

    k0_cvt<<<192, 256, 0, stream>>>(wqkv, g1, wbf);
    k1_qkv<<<1024, 256, 0, stream>>>(x, wbf, qfrag, pS, pC);
    k2_ctx<<<64, 256, 0, stream>>>(pS, pC, wout, MgT);
    k3_out<<<2048, 256, 0, stream>>>(qfrag, MgT, bo, g2, out);
}

// Round 3
// 328.188 us; speedup vs baseline: 1.5994x; 1.5994x over previous
//
#include <hip/hip_runtime.h>
#include <hip/hip_bf16.h>

#define NTOK 16384
#define SQRT_C 11.313708498984761f
#define QSCALE 0.17677669529663687f
#define ROWP 152   // padded LDS row (shorts): 304 B = 76 dw == 12 banks, 16B-aligned

typedef __attribute__((ext_vector_type(8))) short v8s;   // 8 bf16 (4 VGPRs)
typedef __attribute__((ext_vector_type(4))) short v4s;   // 4 bf16 (8B)
typedef __attribute__((ext_vector_type(4))) float v4f;   // 4 fp32

__device__ inline short f2bf(float f) {
    __hip_bfloat16 h = __float2bfloat16(f);
    return __builtin_bit_cast(short, h);
}
__device__ inline float bf2f(short s) {
    unsigned u = ((unsigned)(unsigned short)s) << 16;
    return __builtin_bit_cast(float, u);
}
// LDS-only barrier: orders ds ops across waves WITHOUT draining vmcnt,
// so register prefetch of x stays in flight across tile boundaries.
__device__ inline void lds_barrier() {
    __builtin_amdgcn_sched_barrier(0);
    asm volatile("s_waitcnt lgkmcnt(0)" ::: "memory");
    __builtin_amdgcn_s_barrier();
    __builtin_amdgcn_sched_barrier(0);
}

// ---------------- K0: wbf[o][c] = bf16(w_qkv[o][c] * g1[c])  (g1 folded) -------
__global__ void k0_cvt(const float* __restrict__ wq, const float* __restrict__ g1,
                       short* __restrict__ wbf) {
    int i = blockIdx.x * 256 + threadIdx.x;   // 49152
    wbf[i] = f2bf(wq[i] * g1[i & 127]);
}

// ---------------- K1: qkv MFMA on raw bf16(x); rms-scale folded into logits ----
// grid 1024 = 16 b x 64 chunks of 256 tokens; 256 thr (4 waves); 8 tiles of 32 t.
// launch_bounds(256,2) -> 128 VGPR (proven R1); 128 VGPR + 40448 B LDS both
// permit 4 blocks/CU, grid 1024 = 4/CU. (256,4) forced 64 VGPR -> spills (R2).
__global__ __launch_bounds__(256, 2) void k1_qkv(
    const float* __restrict__ x, const short* __restrict__ wbf,
    short* __restrict__ qfrag, float* __restrict__ pS, float* __restrict__ pC)
{
    __shared__ __align__(16) short xn[32][ROWP];    // bf16(x) [t][c]
    __shared__ __align__(16) short kvbuf[256][40];  // exp(k) rows 0..127, v rows 128..255
    __shared__ __align__(16) short qbufT[32][ROWP]; // q_soft bf16 [t][c]  (transposed)
    __shared__ __align__(16) float nrm[4][32];      // per-wave sumsq partials

    const int tid = threadIdx.x;
    const int lane = tid & 63;
    const int w = tid >> 6;
    const int qd = lane >> 4;          // quad 0..3
    const int lm = lane & 15;
    const int b = blockIdx.x >> 6;
    const int chunk = blockIdx.x & 63;
    const size_t xbase = (size_t)b * 128 * NTOK;
    const int crow = tid >> 3;         // channel sub-row 0..31
    const int tq4 = (tid & 7) * 4;     // token offset within tile

    // preload W A-fragments (g1 pre-folded): rows 96w..96w+95, K=128
    v8s wA[6][4];
    #pragma unroll
    for (int rg = 0; rg < 6; ++rg)
        #pragma unroll
        for (int kk = 0; kk < 4; ++kk)
            wA[rg][kk] = *(const v8s*)(wbf + (96 * w + rg * 16 + lm) * 128 + kk * 32 + qd * 8);

    v4f cacc[2][2];
    #pragma unroll
    for (int i = 0; i < 2; ++i)
        #pragma unroll
        for (int j = 0; j < 2; ++j)
            cacc[i][j] = (v4f){0.f, 0.f, 0.f, 0.f};
    float accSr[6][4] = {};            // in-reg exp(k) row sums (k-rgs only)

    // x register buffer: thread holds channels {32p+crow}, tokens tq4..tq4+3
    v4f xv[4];
    auto loadx = [&](int tt) {
        #pragma unroll
        for (int p = 0; p < 4; ++p)
            xv[p] = *(const v4f*)(x + xbase + (size_t)(p * 32 + crow) * NTOK + tt + tq4);
    };
    loadx(chunk * 256);                // prologue prefetch (tile 0)

    for (int st = 0; st < 8; ++st) {
        const int t0 = chunk * 256 + st * 32;

        // ---- (a) sumsq reduce + bf16 convert + next-tile prefetch ----
        float s[4];
        #pragma unroll
        for (int j = 0; j < 4; ++j) {
            float acc = 0.f;
            #pragma unroll
            for (int p = 0; p < 4; ++p) { float v = xv[p][j]; acc += v * v; }
            s[j] = acc;
        }
        #pragma unroll
        for (int j = 0; j < 4; ++j) {
            s[j] += __shfl_xor(s[j], 8, 64);
            s[j] += __shfl_xor(s[j], 16, 64);
            s[j] += __shfl_xor(s[j], 32, 64);
        }
        if (lane < 8) *(v4f*)&nrm[w][lane * 4] = (v4f){s[0], s[1], s[2], s[3]};
        #pragma unroll
        for (int p = 0; p < 4; ++p)
            #pragma unroll
            for (int j = 0; j < 4; ++j)
                xn[tq4 + j][p * 32 + crow] = f2bf(xv[p][j]);
        if (st < 7) loadx(t0 + 32);    // prefetch next tile
        lds_barrier();

        // ---- (b) qkv MFMA + scl + softmax/exp distribute ----
        v4f C[6][2];
        #pragma unroll
        for (int rg = 0; rg < 6; ++rg) {
            C[rg][0] = (v4f){0.f, 0.f, 0.f, 0.f};
            C[rg][1] = (v4f){0.f, 0.f, 0.f, 0.f};
        }
        #pragma unroll
        for (int kk = 0; kk < 4; ++kk) {
            v8s B0 = *(const v8s*)&xn[lm][kk * 32 + qd * 8];
            v8s B1 = *(const v8s*)&xn[16 + lm][kk * 32 + qd * 8];
            #pragma unroll
            for (int rg = 0; rg < 6; ++rg) {
                C[rg][0] = __builtin_amdgcn_mfma_f32_16x16x32_bf16(wA[rg][kk], B0, C[rg][0], 0, 0, 0);
                C[rg][1] = __builtin_amdgcn_mfma_f32_16x16x32_bf16(wA[rg][kk], B1, C[rg][1], 0, 0, 0);
            }
        }
        // per-token rms scale for this lane's two columns (t = lm, 16+lm)
        float sA = nrm[0][lm] + nrm[1][lm] + nrm[2][lm] + nrm[3][lm];
        float sB = nrm[0][16 + lm] + nrm[1][16 + lm] + nrm[2][16 + lm] + nrm[3][16 + lm];
        float scl0 = SQRT_C / fmaxf(sqrtf(sA), 1e-12f);
        float scl1 = SQRT_C / fmaxf(sqrtf(sB), 1e-12f);

        #pragma unroll
        for (int pr = 0; pr < 3; ++pr) {
            const int R = 96 * w + 32 * pr;
            if (R < 128) {                      // q head (rows R..R+31), softmax over d
                #pragma unroll
                for (int tg = 0; tg < 2; ++tg) {
                    const float sclt = tg ? scl1 : scl0;
                    float e0[4], e1[4];
                    float m = -1e30f;
                    #pragma unroll
                    for (int r = 0; r < 4; ++r) {
                        e0[r] = C[2 * pr][tg][r] * sclt;
                        e1[r] = C[2 * pr + 1][tg][r] * sclt;
                        m = fmaxf(m, fmaxf(e0[r], e1[r]));
                    }
                    m = fmaxf(m, __shfl_xor(m, 16, 64));
                    m = fmaxf(m, __shfl_xor(m, 32, 64));
                    float ssum = 0.f;
                    #pragma unroll
                    for (int r = 0; r < 4; ++r) {
                        e0[r] = __expf(e0[r] - m);
                        e1[r] = __expf(e1[r] - m);
                        ssum += e0[r] + e1[r];
                    }
                    ssum += __shfl_xor(ssum, 16, 64);
                    ssum += __shfl_xor(ssum, 32, 64);
                    const float inv = QSCALE / ssum;
                    const int t = tg * 16 + lm;
                    v4s p0, p1;
                    #pragma unroll
                    for (int r = 0; r < 4; ++r) {
                        p0[r] = f2bf(e0[r] * inv);
                        p1[r] = f2bf(e1[r] * inv);
                    }
                    *(v4s*)&qbufT[t][R + qd * 4] = p0;          // vectorized b64 writes
                    *(v4s*)&qbufT[t][R + 16 + qd * 4] = p1;
                }
            } else {                            // k or v rows
                #pragma unroll
                for (int f = 0; f < 2; ++f) {
                    const int rg = 2 * pr + f;
                    const int R2 = R + 16 * f;
                    const bool isk = (R2 < 256);
                    float part[4] = {0.f, 0.f, 0.f, 0.f};
                    #pragma unroll
                    for (int tg = 0; tg < 2; ++tg) {
                        const float sclt = tg ? scl1 : scl0;
                        const int col = tg * 16 + lm;
                        #pragma unroll
                        for (int r = 0; r < 4; ++r) {
                            float val = C[rg][tg][r] * sclt;
                            if (isk) val = __expf(val);
                            short vb = f2bf(val);
                            kvbuf[R2 - 128 + qd * 4 + r][col] = vb;
                            if (isk) part[r] += bf2f(vb);
                        }
                    }
                    if (isk) {                  // in-reg row-sum of exp(k)
                        #pragma unroll
                        for (int r = 0; r < 4; ++r) {
                            float p = part[r];
                            p += __shfl_xor(p, 1, 64);
                            p += __shfl_xor(p, 2, 64);
                            p += __shfl_xor(p, 4, 64);
                            p += __shfl_xor(p, 8, 64);
                            accSr[rg][r] += p;
                        }
                    }
                }
            }
        }
        lds_barrier();

        // ---- (c) q gather -> global qfrag (vectorized) + context MFMA ----
        {
            const int tb0 = chunk * 16 + st * 2;
            #pragma unroll
            for (int tbl = 0; tbl < 2; ++tbl) {
                v8s pk = *(const v8s*)&qbufT[tbl * 16 + lm][w * 32 + qd * 8];
                *(v8s*)(qfrag + ((((size_t)b * 1024 + tb0 + tbl) * 4 + w) << 9) + lane * 8) = pk;
            }
            v8s A0 = *(const v8s*)&kvbuf[w * 32 + lm][qd * 8];
            v8s A1 = *(const v8s*)&kvbuf[w * 32 + 16 + lm][qd * 8];
            v8s B0 = *(const v8s*)&kvbuf[128 + w * 32 + lm][qd * 8];
            v8s B1 = *(const v8s*)&kvbuf[128 + w * 32 + 16 + lm][qd * 8];
            cacc[0][0] = __builtin_amdgcn_mfma_f32_16x16x32_bf16(A0, B0, cacc[0][0], 0, 0, 0);
            cacc[0][1] = __builtin_amdgcn_mfma_f32_16x16x32_bf16(A0, B1, cacc[0][1], 0, 0, 0);
            cacc[1][0] = __builtin_amdgcn_mfma_f32_16x16x32_bf16(A1, B0, cacc[1][0], 0, 0, 0);
            cacc[1][1] = __builtin_amdgcn_mfma_f32_16x16x32_bf16(A1, B1, cacc[1][1], 0, 0, 0);
        }
    }

    // epilogue: exp(k) row sums (waves 1,2 hold them)
    if ((w == 1 || w == 2) && lm == 0) {
        #pragma unroll
        for (int rg = 0; rg < 6; ++rg) {
            const int R = 96 * w + 16 * rg;
            if (R >= 128 && R < 256) {
                #pragma unroll
                for (int r = 0; r < 4; ++r)
                    pS[(size_t)(b * 64 + chunk) * 128 + (R - 128) + qd * 4 + r] = accSr[rg][r];
            }
        }
    }
    #pragma unroll
    for (int dg = 0; dg < 2; ++dg)
        #pragma unroll
        for (int eg = 0; eg < 2; ++eg)
            #pragma unroll
            for (int r = 0; r < 4; ++r) {
                int d = dg * 16 + qd * 4 + r;
                int e = eg * 16 + lm;
                pC[(size_t)(b * 64 + chunk) * 4096 + w * 1024 + d * 32 + e] = cacc[dg][eg][r];
            }
}

// ---------------- K2: reduce partials -> ctx -> MgT bf16 [b][o][c'] -------------
__global__ void k2_ctx(const float* __restrict__ pS, const float* __restrict__ pC,
                       const float* __restrict__ wout, short* __restrict__ MgT) {
    __shared__ float ctx[32][33];
    __shared__ float Sv[32];
    const int tid = threadIdx.x;
    const int b = blockIdx.x >> 2, h = blockIdx.x & 3;
    if (tid < 32) {
        float s = 0.f;
        for (int ch = 0; ch < 64; ++ch) s += pS[(size_t)(b * 64 + ch) * 128 + h * 32 + tid];
        Sv[tid] = s;
    }
    __syncthreads();
    #pragma unroll
    for (int k = 0; k < 4; ++k) {
        int de = tid + k * 256;
        float s = 0.f;
        for (int ch = 0; ch < 64; ++ch) s += pC[(size_t)(b * 64 + ch) * 4096 + h * 1024 + de];
        ctx[de >> 5][de & 31] = s / Sv[de >> 5];
    }
    __syncthreads();
    // M[h*32+d][o] = sum_e wout[o][h*32+e] * ctx[d][e]; store transposed bf16 at [o][h*32+d]
    #pragma unroll
    for (int k = 0; k < 16; ++k) {
        int idx = tid + k * 256;
        int d = idx & 31, o = idx >> 5;
        float m = 0.f;
        #pragma unroll
        for (int e = 0; e < 32; ++e) m += wout[o * 128 + h * 32 + e] * ctx[d][e];
        MgT[((size_t)b * 128 + o) * 128 + h * 32 + d] = f2bf(m);
    }
}

// ---------------- K3: y = M_b @ q_soft + b_out -> rmsnorm(g2) (MFMA) ------------
// grid 2048 = 16 b x 128 chunks of 128 tokens; wave w owns rows 32w..32w+31
__global__ __launch_bounds__(256) void k3_out(
    const short* __restrict__ qfrag, const short* __restrict__ MgT,
    const float* __restrict__ bo, const float* __restrict__ g2,
    float* __restrict__ out)
{
    __shared__ float part[4][128];
    __shared__ float scl[128];
    const int tid = threadIdx.x;
    const int lane = tid & 63, w = tid >> 6;
    const int qd = lane >> 4, lm = lane & 15;
    const int b = blockIdx.x >> 7;
    const int t0 = (blockIdx.x & 127) << 7;
    const int tb0 = t0 >> 4;

    v8s A[2][4];
    #pragma unroll
    for (int rg = 0; rg < 2; ++rg)
        #pragma unroll
        for (int kk = 0; kk < 4; ++kk)
            A[rg][kk] = *(const v8s*)(MgT + ((size_t)b * 128 + 32 * w + rg * 16 + lm) * 128 + kk * 32 + qd * 8);

    v4f C[2][8];
    #pragma unroll
    for (int rg = 0; rg < 2; ++rg)
        #pragma unroll
        for (int tb = 0; tb < 8; ++tb)
            C[rg][tb] = (v4f){0.f, 0.f, 0.f, 0.f};

    #pragma unroll
    for (int tb = 0; tb < 8; ++tb)
        #pragma unroll
        for (int kk = 0; kk < 4; ++kk) {
            v8s B = *(const v8s*)(qfrag + ((((size_t)b * 1024 + tb0 + tb) * 4 + kk) << 9) + lane * 8);
            C[0][tb] = __builtin_amdgcn_mfma_f32_16x16x32_bf16(A[0][kk], B, C[0][tb], 0, 0, 0);
            C[1][tb] = __builtin_amdgcn_mfma_f32_16x16x32_bf16(A[1][kk], B, C[1][tb], 0, 0, 0);
        }

    float bov[2][4], g2v[2][4];
    #pragma unroll
    for (int rg = 0; rg < 2; ++rg)
        #pragma unroll
        for (int r = 0; r < 4; ++r) {
            int o = 32 * w + rg * 16 + qd * 4 + r;
            bov[rg][r] = bo[o];
            g2v[rg][r] = g2[o];
        }
    // bias + per-token sumsq (reduce 32 rows via xor shuffles, cross-wave via LDS)
    #pragma unroll
    for (int tb = 0; tb < 8; ++tb) {
        float ss = 0.f;
        #pragma unroll
        for (int rg = 0; rg < 2; ++rg)
            #pragma unroll
            for (int r = 0; r < 4; ++r) {
                C[rg][tb][r] += bov[rg][r];
                ss += C[rg][tb][r] * C[rg][tb][r];
            }
        ss += __shfl_xor(ss, 16, 64);
        ss += __shfl_xor(ss, 32, 64);
        if (lane < 16) part[w][tb * 16 + lane] = ss;
    }
    __syncthreads();
    if (tid < 128) {
        float s = part[0][tid] + part[1][tid] + part[2][tid] + part[3][tid];
        scl[tid] = SQRT_C / fmaxf(sqrtf(s), 1e-12f);
    }
    __syncthreads();
    #pragma unroll
    for (int tb = 0; tb < 8; ++tb) {
        float sc = scl[tb * 16 + lm];
        #pragma unroll
        for (int rg = 0; rg < 2; ++rg)
            #pragma unroll
            for (int r = 0; r < 4; ++r) {
                int o = 32 * w + rg * 16 + qd * 4 + r;
                out[((size_t)b * 128 + o) * NTOK + t0 + tb * 16 + lm] = C[rg][tb][r] * sc * g2v[rg][r];
            }
    }
}

extern "C" void kernel_launch(void* const* d_in, const int* in_sizes, int n_in,
                              void* d_out, int out_size, void* d_ws, size_t ws_size,
                              hipStream_t stream) {
    const float* x    = (const float*)d_in[0];
    const float* g1   = (const float*)d_in[1];
    const float* wqkv = (const float*)d_in[2];
    const float* wout = (const float*)d_in[3];
    const float* bo   = (const float*)d_in[4];
    const float* g2   = (const float*)d_in[5];
    float* out = (float*)d_out;
    char* ws = (char*)d_ws;
    // ws: qfrag bf16 [16][1024][4][512] @0 (67,108,864 B)
    //     pS fp32 [16][64][128]  @67,108,864 (524,288)
    //     pC fp32 [16][64][4096] @67,633,152 (16,777,216)
    //     MgT bf16 [16][128][128] @84,410,368 (524,288)
    //     wbf bf16 [384][128]     @84,934,656 (98,304)   total 85,032,960 B
    short* qfrag = (short*)ws;
    float* pS = (float*)(ws + 67108864);
    float* pC = (float*)(ws + 67633152);
    short* MgT = (short*)(ws + 84410368);
    short* wbf = (short*)(ws + 84934656);

    k0_cvt<<<192, 256, 0, stream>>>(wqkv, g1, wbf);
    k1_qkv<<<1024, 256, 0, stream>>>(x, wbf, qfrag, pS, pC);
    k2_ctx<<<64, 256, 0, stream>>>(pS, pC, wout, MgT);
    k3_out<<<2048, 256, 0, stream>>>(qfrag, MgT, bo, g2, out);
}